// Round 3
// baseline (233.268 us; speedup 1.0000x reference)
//
#include <hip/hip_runtime.h>

#define Dc 256
#define Bc 4
#define Fc 60082
#define KNc 64
#define KHc 128

typedef __attribute__((ext_vector_type(4))) float f32x4;

// workspace layout (floats):
//   [0,256)    u  = W_proj @ w_ff
//   [256,384)  v2 = W2 @ w_ff
//   [384,388)  constb[b] = company_out[b] + b_fc + b_ff
//   [388]      c2 = b2 . w_ff
//   [389]      c0 = b_proj . w_ff
//   [512,512+F) s[f] = field_table[f] . u + c0

__device__ __forceinline__ float wave_reduce_sum_bfly(float v) {
    #pragma unroll
    for (int off = 32; off > 0; off >>= 1)
        v += __shfl_xor(v, off, 64);
    return v;   // all lanes hold the sum
}

// 390 independent length-256 dot products, one wave each.
__global__ void k_pre(const float* __restrict__ company_emb,
                      const float* __restrict__ comp_table,
                      const float* __restrict__ W_proj,
                      const float* __restrict__ b_proj,
                      const float* __restrict__ theta,
                      const float* __restrict__ w_ff,
                      const float* __restrict__ b_ff,
                      const float* __restrict__ w_fc,
                      const float* __restrict__ b_fc,
                      const float* __restrict__ W2,
                      const float* __restrict__ b2,
                      const int* __restrict__ com_id,
                      float* __restrict__ ws)
{
    int gw = (blockIdx.x * blockDim.x + threadIdx.x) >> 6;
    int lane = threadIdx.x & 63;
    if (gw >= 390) return;

    const float4* wf4 = (const float4*)w_ff;
    float val = 0.f;
    float addend = 0.f;
    float* dst;

    if (gw < 256) {                       // u
        float4 a = ((const float4*)(W_proj + (size_t)gw * Dc))[lane];
        float4 b = wf4[lane];
        val = a.x*b.x + a.y*b.y + a.z*b.z + a.w*b.w;
        dst = ws + gw;
    } else if (gw < 384) {                // v2
        int j = gw - 256;
        float4 a = ((const float4*)(W2 + (size_t)j * Dc))[lane];
        float4 b = wf4[lane];
        val = a.x*b.x + a.y*b.y + a.z*b.z + a.w*b.w;
        dst = ws + 256 + j;
    } else if (gw < 388) {                // constb
        int b_ = gw - 384;
        int cid = com_id[b_];
        float th = theta[cid];
        float4 x = ((const float4*)(company_emb + (size_t)b_ * Dc))[lane];
        float4 y = ((const float4*)(comp_table + (size_t)cid * Dc))[lane];
        float4 w = ((const float4*)w_fc)[lane];
        float4 m;
        m.x = (1.f - th) * x.x + th * y.x;
        m.y = (1.f - th) * x.y + th * y.y;
        m.z = (1.f - th) * x.z + th * y.z;
        m.w = (1.f - th) * x.w + th * y.w;
        val = m.x*w.x + m.y*w.y + m.z*w.z + m.w*w.w;
        addend = b_fc[0] + b_ff[0];
        dst = ws + 384 + b_;
    } else if (gw == 388) {               // c2 = b2 . w_ff
        float4 a = ((const float4*)b2)[lane];
        float4 b = wf4[lane];
        val = a.x*b.x + a.y*b.y + a.z*b.z + a.w*b.w;
        dst = ws + 388;
    } else {                              // c0 = b_proj . w_ff
        float4 a = ((const float4*)b_proj)[lane];
        float4 b = wf4[lane];
        val = a.x*b.x + a.y*b.y + a.z*b.z + a.w*b.w;
        dst = ws + 389;
    }
    val = wave_reduce_sum_bfly(val);
    if (lane == 0) *dst = val + addend;
}

#define RPW 8
// one wave per 8 field rows: s[f] = field_table[f,:].u + c0, and fused
// broadcast write out[b*F+f] = s[f] + constb[b].
// 8 independent nontemporal float4 loads in flight per lane before reduce.
__global__ void k_s(const float* __restrict__ field_table,
                    const float* __restrict__ ws,
                    float* __restrict__ s,
                    float* __restrict__ out)
{
    int gw = (blockIdx.x * blockDim.x + threadIdx.x) >> 6;
    int lane = threadIdx.x & 63;
    int f0 = gw * RPW;
    if (f0 >= Fc) return;

    float4 b = ((const float4*)ws)[lane];
    float c0 = ws[389];

    float acc[RPW];
    #pragma unroll
    for (int r = 0; r < RPW; ++r) {
        int f = f0 + r;
        f32x4 a = (f32x4){0.f, 0.f, 0.f, 0.f};
        if (f < Fc)
            a = __builtin_nontemporal_load(
                    (const f32x4*)(field_table + (size_t)f * Dc) + lane);
        acc[r] = a.x*b.x + a.y*b.y + a.z*b.z + a.w*b.w;
    }
    #pragma unroll
    for (int r = 0; r < RPW; ++r)
        acc[r] = wave_reduce_sum_bfly(acc[r]);

    // all lanes hold all 8 sums; select by runtime index via cndmask chain
    auto pick = [&](int i) {
        float v = acc[0];
        #pragma unroll
        for (int r = 1; r < RPW; ++r)
            v = (i == r) ? acc[r] : v;
        return v;
    };

    if (lane < 32) {            // out writes: lane = bb*8 + r  (32B runs per b-row)
        int r  = lane & 7;
        int bb = lane >> 3;
        int f  = f0 + r;
        if (f < Fc) out[(size_t)bb * Fc + f] = pick(r) + c0 + ws[384 + bb];
    } else if (lane < 40) {     // s writes
        int r = lane - 32;
        int f = f0 + r;
        if (f < Fc) s[f] = pick(r) + c0;
    }
}

// one wave per (b, node-slot): overwrite marked positions with full final value
__global__ void k_fix(const float* __restrict__ field_emb,
                      const float* __restrict__ raw_field_embed,
                      const float* __restrict__ alpha_fields,
                      const float* __restrict__ w_ff,
                      const float* __restrict__ W1,
                      const float* __restrict__ b1,
                      const float* __restrict__ ws,   // u/v2/constb/scal
                      const float* __restrict__ s,
                      const int* __restrict__ now_nodes,
                      const int* __restrict__ his_nodes,
                      float* __restrict__ out)
{
    const float* v2     = ws + 256;
    const float* constb = ws + 384;
    const float* scal   = ws + 388;

    const int NPB = KNc + KHc; // 192 node slots per b
    int gw = (blockIdx.x * blockDim.x + threadIdx.x) >> 6;
    int lane = threadIdx.x & 63;
    if (gw >= Bc * NPB) return;
    int b = gw / NPB;
    int k = gw - b * NPB;
    int f = (k < KNc) ? now_nodes[b * KNc + k]
                      : his_nodes[b * KHc + (k - KNc)];

    // membership tests (wave-cooperative scans)
    int nn = now_nodes[b * KNc + lane];
    bool in_now = __any(nn == f);
    int h0 = his_nodes[b * KHc + lane];
    int h1 = his_nodes[b * KHc + 64 + lane];
    bool in_his = __any((h0 == f) || (h1 == f));

    float alpha = alpha_fields[f];
    float val = (1.f - alpha) * s[f] + constb[b];

    if (in_now) {
        float4 a  = ((const float4*)(field_emb + (size_t)f * Dc))[lane];
        float4 ww = ((const float4*)w_ff)[lane];
        float acc = a.x*ww.x + a.y*ww.y + a.z*ww.z + a.w*ww.w;
        acc = wave_reduce_sum_bfly(acc);
        val += alpha * acc;
    }
    if (in_his) {
        // g = leaky(raw_field_embed[f,:] @ W1 + b1);  hf = g . v2 + c2
        float acc0 = 0.f, acc1 = 0.f;
        const float4* raw4 = (const float4*)(raw_field_embed + (size_t)f * Dc);
        #pragma unroll 2
        for (int d4 = 0; d4 < Dc / 4; ++d4) {
            float4 r4 = raw4[d4];
            const float* base = W1 + d4 * 4 * 128;
            acc0 += r4.x * base[lane]       + r4.y * base[128 + lane]
                  + r4.z * base[256 + lane] + r4.w * base[384 + lane];
            acc1 += r4.x * base[64 + lane]      + r4.y * base[128 + 64 + lane]
                  + r4.z * base[256 + 64 + lane] + r4.w * base[384 + 64 + lane];
        }
        float g0 = acc0 + b1[lane];
        float g1 = acc1 + b1[64 + lane];
        g0 = (g0 >= 0.f) ? g0 : 0.01f * g0;
        g1 = (g1 >= 0.f) ? g1 : 0.01f * g1;
        float p = g0 * v2[lane] + g1 * v2[64 + lane];
        p = wave_reduce_sum_bfly(p);
        val += alpha * (p + scal[0]);
    }
    if (lane == 0) out[(size_t)b * Fc + f] = val;
}

extern "C" void kernel_launch(void* const* d_in, const int* in_sizes, int n_in,
                              void* d_out, int out_size, void* d_ws, size_t ws_size,
                              hipStream_t stream) {
    const float* company_emb     = (const float*)d_in[0];
    const float* field_emb       = (const float*)d_in[1];
    const float* raw_field_embed = (const float*)d_in[2];
    const float* comp_table      = (const float*)d_in[3];
    const float* field_table     = (const float*)d_in[4];
    const float* W_proj          = (const float*)d_in[5];
    const float* b_proj          = (const float*)d_in[6];
    const float* theta           = (const float*)d_in[7];
    const float* alpha_fields    = (const float*)d_in[8];
    const float* w_ff            = (const float*)d_in[9];
    const float* b_ff            = (const float*)d_in[10];
    const float* w_fc            = (const float*)d_in[11];
    const float* b_fc            = (const float*)d_in[12];
    const float* W1              = (const float*)d_in[13];
    const float* b1              = (const float*)d_in[14];
    const float* W2              = (const float*)d_in[15];
    const float* b2              = (const float*)d_in[16];
    const int*   now_nodes       = (const int*)d_in[17];
    const int*   his_nodes       = (const int*)d_in[18];
    const int*   com_id          = (const int*)d_in[19];

    float* ws  = (float*)d_ws;
    float* s   = ws + 512;
    float* out = (float*)d_out;

    // 390 waves -> 98 blocks of 4 waves
    k_pre<<<(390 + 3) / 4, 256, 0, stream>>>(company_emb, comp_table, W_proj, b_proj,
                                             theta, w_ff, b_ff, w_fc, b_fc, W2, b2,
                                             com_id, ws);

    // one wave per 8 rows
    int waves = (Fc + RPW - 1) / RPW;
    k_s<<<(waves + 3) / 4, 256, 0, stream>>>(field_table, ws, s, out);

    // one wave per node slot
    int fix_blocks = (Bc * (KNc + KHc)) / 4;
    k_fix<<<fix_blocks, 256, 0, stream>>>(field_emb, raw_field_embed, alpha_fields,
                                          w_ff, W1, b1, ws, s,
                                          now_nodes, his_nodes, out);
}

// Round 4
// 219.801 us; speedup vs baseline: 1.0613x; 1.0613x over previous
//
#include <hip/hip_runtime.h>

#define Dc 256
#define Bc 4
#define Fc 60082
#define KNc 64
#define KHc 128

// workspace layout (floats):
//   [0,256)    u  = W_proj @ w_ff
//   [256,384)  v2 = W2 @ w_ff
//   [384,388)  constb[b] = company_out[b] + b_fc + b_ff
//   [388]      c2 = b2 . w_ff
//   [389]      c0 = b_proj . w_ff
//   [512,512+F) s[f] = field_table[f] . u + c0

__device__ __forceinline__ float wave_reduce_sum_bfly(float v) {
    #pragma unroll
    for (int off = 32; off > 0; off >>= 1)
        v += __shfl_xor(v, off, 64);
    return v;   // all lanes hold the sum
}

// 390 independent length-256 dot products, one wave each.
__global__ void k_pre(const float* __restrict__ company_emb,
                      const float* __restrict__ comp_table,
                      const float* __restrict__ W_proj,
                      const float* __restrict__ b_proj,
                      const float* __restrict__ theta,
                      const float* __restrict__ w_ff,
                      const float* __restrict__ b_ff,
                      const float* __restrict__ w_fc,
                      const float* __restrict__ b_fc,
                      const float* __restrict__ W2,
                      const float* __restrict__ b2,
                      const int* __restrict__ com_id,
                      float* __restrict__ ws)
{
    int gw = (blockIdx.x * blockDim.x + threadIdx.x) >> 6;
    int lane = threadIdx.x & 63;
    if (gw >= 390) return;

    const float4* wf4 = (const float4*)w_ff;
    float val = 0.f;
    float addend = 0.f;
    float* dst;

    if (gw < 256) {                       // u
        float4 a = ((const float4*)(W_proj + (size_t)gw * Dc))[lane];
        float4 b = wf4[lane];
        val = a.x*b.x + a.y*b.y + a.z*b.z + a.w*b.w;
        dst = ws + gw;
    } else if (gw < 384) {                // v2
        int j = gw - 256;
        float4 a = ((const float4*)(W2 + (size_t)j * Dc))[lane];
        float4 b = wf4[lane];
        val = a.x*b.x + a.y*b.y + a.z*b.z + a.w*b.w;
        dst = ws + 256 + j;
    } else if (gw < 388) {                // constb
        int b_ = gw - 384;
        int cid = com_id[b_];
        float th = theta[cid];
        float4 x = ((const float4*)(company_emb + (size_t)b_ * Dc))[lane];
        float4 y = ((const float4*)(comp_table + (size_t)cid * Dc))[lane];
        float4 w = ((const float4*)w_fc)[lane];
        float4 m;
        m.x = (1.f - th) * x.x + th * y.x;
        m.y = (1.f - th) * x.y + th * y.y;
        m.z = (1.f - th) * x.z + th * y.z;
        m.w = (1.f - th) * x.w + th * y.w;
        val = m.x*w.x + m.y*w.y + m.z*w.z + m.w*w.w;
        addend = b_fc[0] + b_ff[0];
        dst = ws + 384 + b_;
    } else if (gw == 388) {               // c2 = b2 . w_ff
        float4 a = ((const float4*)b2)[lane];
        float4 b = wf4[lane];
        val = a.x*b.x + a.y*b.y + a.z*b.z + a.w*b.w;
        dst = ws + 388;
    } else {                              // c0 = b_proj . w_ff
        float4 a = ((const float4*)b_proj)[lane];
        float4 b = wf4[lane];
        val = a.x*b.x + a.y*b.y + a.z*b.z + a.w*b.w;
        dst = ws + 389;
    }
    val = wave_reduce_sum_bfly(val);
    if (lane == 0) *dst = val + addend;
}

#define RPW 8   // rows per wave (2 passes of 4 rows, 16 lanes per row)
// lane = 16*sub + c. Row f = f0 + pass*4 + sub. Lane loads row float4s at
// columns {c, c+16, c+32, c+48} (coalesced 256B segments) and reduces across
// its 16-lane group in 4 butterfly stages -> sum broadcast to all 16 lanes.
// Fused broadcast write: c<4 writes out[c*F+f], c==4 writes s[f].
__global__ void k_s(const float* __restrict__ field_table,
                    const float* __restrict__ ws,
                    float* __restrict__ s,
                    float* __restrict__ out)
{
    int gw = (blockIdx.x * blockDim.x + threadIdx.x) >> 6;
    int lane = threadIdx.x & 63;
    int f0 = gw * RPW;
    if (f0 >= Fc) return;

    int sub = lane >> 4;      // which of the 4 rows in a pass
    int c   = lane & 15;      // column slot within the row

    // u fragments for this lane's column slots (u = ws[0..256), 64 float4)
    const float4* u4 = (const float4*)ws;
    float4 b0 = u4[c];
    float4 b1 = u4[c + 16];
    float4 b2 = u4[c + 32];
    float4 b3 = u4[c + 48];
    float c0 = ws[389];

    float sums[2];
    #pragma unroll
    for (int pass = 0; pass < 2; ++pass) {
        int f = f0 + pass * 4 + sub;
        float4 a0, a1, a2, a3;
        if (f < Fc) {
            const float4* row = (const float4*)(field_table + (size_t)f * Dc);
            a0 = row[c];
            a1 = row[c + 16];
            a2 = row[c + 32];
            a3 = row[c + 48];
        } else {
            a0 = a1 = a2 = a3 = make_float4(0.f, 0.f, 0.f, 0.f);
        }
        float acc = a0.x*b0.x + a0.y*b0.y + a0.z*b0.z + a0.w*b0.w
                  + a1.x*b1.x + a1.y*b1.y + a1.z*b1.z + a1.w*b1.w
                  + a2.x*b2.x + a2.y*b2.y + a2.z*b2.z + a2.w*b2.w
                  + a3.x*b3.x + a3.y*b3.y + a3.z*b3.z + a3.w*b3.w;
        // reduce within the 16-lane row group (stays inside the group)
        acc += __shfl_xor(acc, 1, 64);
        acc += __shfl_xor(acc, 2, 64);
        acc += __shfl_xor(acc, 4, 64);
        acc += __shfl_xor(acc, 8, 64);
        sums[pass] = acc;     // all 16 lanes of the group hold the row sum
    }

    #pragma unroll
    for (int pass = 0; pass < 2; ++pass) {
        int f = f0 + pass * 4 + sub;
        if (f >= Fc) continue;
        float sv = sums[pass] + c0;
        if (c < Bc) {
            out[(size_t)c * Fc + f] = sv + ws[384 + c];
        } else if (c == Bc) {
            s[f] = sv;
        }
    }
}

// one wave per (b, node-slot): overwrite marked positions with full final value
__global__ void k_fix(const float* __restrict__ field_emb,
                      const float* __restrict__ raw_field_embed,
                      const float* __restrict__ alpha_fields,
                      const float* __restrict__ w_ff,
                      const float* __restrict__ W1,
                      const float* __restrict__ b1,
                      const float* __restrict__ ws,   // u/v2/constb/scal
                      const float* __restrict__ s,
                      const int* __restrict__ now_nodes,
                      const int* __restrict__ his_nodes,
                      float* __restrict__ out)
{
    const float* v2     = ws + 256;
    const float* constb = ws + 384;
    const float* scal   = ws + 388;

    const int NPB = KNc + KHc; // 192 node slots per b
    int gw = (blockIdx.x * blockDim.x + threadIdx.x) >> 6;
    int lane = threadIdx.x & 63;
    if (gw >= Bc * NPB) return;
    int b = gw / NPB;
    int k = gw - b * NPB;
    int f = (k < KNc) ? now_nodes[b * KNc + k]
                      : his_nodes[b * KHc + (k - KNc)];

    // membership tests (wave-cooperative scans)
    int nn = now_nodes[b * KNc + lane];
    bool in_now = __any(nn == f);
    int h0 = his_nodes[b * KHc + lane];
    int h1 = his_nodes[b * KHc + 64 + lane];
    bool in_his = __any((h0 == f) || (h1 == f));

    float alpha = alpha_fields[f];
    float val = (1.f - alpha) * s[f] + constb[b];

    if (in_now) {
        float4 a  = ((const float4*)(field_emb + (size_t)f * Dc))[lane];
        float4 ww = ((const float4*)w_ff)[lane];
        float acc = a.x*ww.x + a.y*ww.y + a.z*ww.z + a.w*ww.w;
        acc = wave_reduce_sum_bfly(acc);
        val += alpha * acc;
    }
    if (in_his) {
        // g = leaky(raw_field_embed[f,:] @ W1 + b1);  hf = g . v2 + c2
        float acc0 = 0.f, acc1 = 0.f;
        const float4* raw4 = (const float4*)(raw_field_embed + (size_t)f * Dc);
        #pragma unroll 2
        for (int d4 = 0; d4 < Dc / 4; ++d4) {
            float4 r4 = raw4[d4];
            const float* base = W1 + d4 * 4 * 128;
            acc0 += r4.x * base[lane]       + r4.y * base[128 + lane]
                  + r4.z * base[256 + lane] + r4.w * base[384 + lane];
            acc1 += r4.x * base[64 + lane]      + r4.y * base[128 + 64 + lane]
                  + r4.z * base[256 + 64 + lane] + r4.w * base[384 + 64 + lane];
        }
        float g0 = acc0 + b1[lane];
        float g1 = acc1 + b1[64 + lane];
        g0 = (g0 >= 0.f) ? g0 : 0.01f * g0;
        g1 = (g1 >= 0.f) ? g1 : 0.01f * g1;
        float p = g0 * v2[lane] + g1 * v2[64 + lane];
        p = wave_reduce_sum_bfly(p);
        val += alpha * (p + scal[0]);
    }
    if (lane == 0) out[(size_t)b * Fc + f] = val;
}

extern "C" void kernel_launch(void* const* d_in, const int* in_sizes, int n_in,
                              void* d_out, int out_size, void* d_ws, size_t ws_size,
                              hipStream_t stream) {
    const float* company_emb     = (const float*)d_in[0];
    const float* field_emb       = (const float*)d_in[1];
    const float* raw_field_embed = (const float*)d_in[2];
    const float* comp_table      = (const float*)d_in[3];
    const float* field_table     = (const float*)d_in[4];
    const float* W_proj          = (const float*)d_in[5];
    const float* b_proj          = (const float*)d_in[6];
    const float* theta           = (const float*)d_in[7];
    const float* alpha_fields    = (const float*)d_in[8];
    const float* w_ff            = (const float*)d_in[9];
    const float* b_ff            = (const float*)d_in[10];
    const float* w_fc            = (const float*)d_in[11];
    const float* b_fc            = (const float*)d_in[12];
    const float* W1              = (const float*)d_in[13];
    const float* b1              = (const float*)d_in[14];
    const float* W2              = (const float*)d_in[15];
    const float* b2              = (const float*)d_in[16];
    const int*   now_nodes       = (const int*)d_in[17];
    const int*   his_nodes       = (const int*)d_in[18];
    const int*   com_id          = (const int*)d_in[19];

    float* ws  = (float*)d_ws;
    float* s   = ws + 512;
    float* out = (float*)d_out;

    // 390 waves -> 98 blocks of 4 waves
    k_pre<<<(390 + 3) / 4, 256, 0, stream>>>(company_emb, comp_table, W_proj, b_proj,
                                             theta, w_ff, b_ff, w_fc, b_fc, W2, b2,
                                             com_id, ws);

    // one wave per 8 rows
    int waves = (Fc + RPW - 1) / RPW;
    k_s<<<(waves + 3) / 4, 256, 0, stream>>>(field_table, ws, s, out);

    // one wave per node slot
    int fix_blocks = (Bc * (KNc + KHc)) / 4;
    k_fix<<<fix_blocks, 256, 0, stream>>>(field_emb, raw_field_embed, alpha_fields,
                                          w_ff, W1, b1, ws, s,
                                          now_nodes, his_nodes, out);
}